// Round 2
// baseline (599.516 us; speedup 1.0000x reference)
//
#include <hip/hip_runtime.h>
#include <hip/hip_bf16.h>

#define Bb 4
#define Cc 256
#define Nn 4096

typedef short s16x8 __attribute__((ext_vector_type(8)));
typedef short s16x4 __attribute__((ext_vector_type(4)));
typedef float f32x4 __attribute__((ext_vector_type(4)));

__device__ __forceinline__ unsigned short f2bf(float f) {
    unsigned u = __builtin_bit_cast(unsigned, f);
    u += 0x7FFFu + ((u >> 16) & 1u);
    return (unsigned short)(u >> 16);
}
__device__ __forceinline__ float bf2f(unsigned short u) {
    unsigned v = ((unsigned)u) << 16;
    return __builtin_bit_cast(float, v);
}

__device__ __forceinline__ f32x4 mfma16(s16x8 a, s16x8 b, f32x4 c) {
    return __builtin_amdgcn_mfma_f32_16x16x32_bf16(a, b, c, 0, 0, 0);
}

// async global->LDS, 16B per lane, dest = uniform base + lane*16
#if __has_builtin(__builtin_amdgcn_global_load_lds)
#define GL16(g, sdst)                                                              \
    __builtin_amdgcn_global_load_lds(                                              \
        (const __attribute__((address_space(1))) unsigned int*)(g),                \
        (__attribute__((address_space(3))) unsigned int*)(sdst), 16, 0, 0)
#else
#define GL16(g, sdst)                                                              \
    do {                                                                           \
        *(s16x8*)((char*)(sdst) + (threadIdx.x & 63) * 16) = *(const s16x8*)(g);   \
    } while (0)
#endif

// ---------------- prep: W fp32 -> bf16 ----------------
__global__ void prep_w(const float* __restrict__ Wq, const float* __restrict__ Wk,
                       const float* __restrict__ Wv, unsigned short* __restrict__ Wbf) {
    int idx = (blockIdx.x * 256 + threadIdx.x) * 8;  // < 3*65536
    int mat = idx >> 16;
    int off = idx & 65535;
    const float* src = (mat == 0) ? Wq : ((mat == 1) ? Wk : Wv);
    float4 a = *(const float4*)(src + off);
    float4 b = *(const float4*)(src + off + 4);
    s16x8 o;
    o[0] = (short)f2bf(a.x); o[1] = (short)f2bf(a.y);
    o[2] = (short)f2bf(a.z); o[3] = (short)f2bf(a.w);
    o[4] = (short)f2bf(b.x); o[5] = (short)f2bf(b.y);
    o[6] = (short)f2bf(b.z); o[7] = (short)f2bf(b.w);
    *(s16x8*)(Wbf + idx) = o;
}

// ---------------- transpose: x[b][c][n] fp32 -> xT[b][n][c] bf16 ----------------
__global__ void transpose_x(const float* __restrict__ x, unsigned short* __restrict__ xT) {
    int b = blockIdx.z, c0 = blockIdx.y * 64, n0 = blockIdx.x * 64;
    __shared__ float tile[64][65];
    int t = threadIdx.x;
    int r = t >> 2, q = t & 3;
    const float* src = x + ((size_t)(b * Cc + c0 + r)) * Nn + n0 + q * 16;
#pragma unroll
    for (int j = 0; j < 4; j++) {
        float4 v4 = *(const float4*)(src + j * 4);
        tile[r][q * 16 + j * 4 + 0] = v4.x;
        tile[r][q * 16 + j * 4 + 1] = v4.y;
        tile[r][q * 16 + j * 4 + 2] = v4.z;
        tile[r][q * 16 + j * 4 + 3] = v4.w;
    }
    __syncthreads();
    unsigned short* dst = xT + ((size_t)b * Nn + n0 + r) * Cc + c0 + q * 16;
    s16x8 o0, o1;
#pragma unroll
    for (int j = 0; j < 8; j++) o0[j] = (short)f2bf(tile[q * 16 + j][r]);
#pragma unroll
    for (int j = 0; j < 8; j++) o1[j] = (short)f2bf(tile[q * 16 + 8 + j][r]);
    *(s16x8*)dst = o0;
    *(s16x8*)(dst + 8) = o1;
}

// ---------------- projections ----------------
__global__ void proj(const unsigned short* __restrict__ xT, const unsigned short* __restrict__ Wbf,
                     const float* __restrict__ bq, const float* __restrict__ bk,
                     const float* __restrict__ bv,
                     unsigned short* __restrict__ qT, unsigned short* __restrict__ kT,
                     unsigned short* __restrict__ vO) {
    int nt0 = blockIdx.x * 64;
    int mat = blockIdx.y;
    int b   = blockIdx.z;
    int t = threadIdx.x, w = t >> 6, l = t & 63;
    int lr = l & 15, lg = l >> 4;
    const unsigned short* Wm  = Wbf + mat * (Cc * Cc);
    const float* bias = (mat == 0) ? bq : ((mat == 1) ? bk : bv);
    const unsigned short* xTb = xT + (size_t)b * Nn * Cc;

    if (mat < 2) {
        unsigned short* out = ((mat == 0) ? qT : kT) + (size_t)b * Nn * Cc;
        int nrow = nt0 + w * 16;
        s16x8 af[8];
#pragma unroll
        for (int kk = 0; kk < 8; kk++)
            af[kk] = *(const s16x8*)(xTb + (nrow + lr) * Cc + kk * 32 + lg * 8);
        for (int ct = 0; ct < 16; ct++) {
            f32x4 acca = {0, 0, 0, 0}, accb = {0, 0, 0, 0};
#pragma unroll
            for (int kk = 0; kk < 8; kk += 2) {
                s16x8 bfa = *(const s16x8*)(Wm + (ct * 16 + lr) * Cc + kk * 32 + lg * 8);
                s16x8 bfb = *(const s16x8*)(Wm + (ct * 16 + lr) * Cc + (kk + 1) * 32 + lg * 8);
                acca = mfma16(af[kk], bfa, acca);
                accb = mfma16(af[kk + 1], bfb, accb);
            }
            f32x4 acc = acca + accb;
            float bb = bias[ct * 16 + lr];
#pragma unroll
            for (int r = 0; r < 4; r++)
                out[(nrow + lg * 4 + r) * Cc + ct * 16 + lr] = f2bf(acc[r] + bb);
        }
    } else {
        unsigned short* out = vO + (size_t)b * Cc * Nn;
        for (int mt = 0; mt < 4; mt++) {
            int crow = (w * 4 + mt) * 16;
            s16x8 af[8];
#pragma unroll
            for (int kk = 0; kk < 8; kk++)
                af[kk] = *(const s16x8*)(Wm + (crow + lr) * Cc + kk * 32 + lg * 8);
#pragma unroll
            for (int nt = 0; nt < 4; nt++) {
                f32x4 acca = {0, 0, 0, 0}, accb = {0, 0, 0, 0};
#pragma unroll
                for (int kk = 0; kk < 8; kk += 2) {
                    s16x8 bfa = *(const s16x8*)(xTb + (nt0 + nt * 16 + lr) * Cc + kk * 32 + lg * 8);
                    s16x8 bfb = *(const s16x8*)(xTb + (nt0 + nt * 16 + lr) * Cc + (kk + 1) * 32 + lg * 8);
                    acca = mfma16(af[kk], bfa, acca);
                    accb = mfma16(af[kk + 1], bfb, accb);
                }
                f32x4 acc = acca + accb;
#pragma unroll
                for (int r = 0; r < 4; r++) {
                    float bb = bias[crow + lg * 4 + r];
                    out[(size_t)(crow + lg * 4 + r) * Nn + nt0 + nt * 16 + lr] = f2bf(acc[r] + bb);
                }
            }
        }
    }
}

// ---------------- fused flash attention, split over j ----------------
// grid.x = b*S + s (XCD-pinned: %8 groups share K/V slices in one XCD's L2)
// Per wave: 16 i-rows. K-tile staged to LDS (swizzled, shared by 4 waves);
// V direct from L2. Shift-free softmax: p = exp(E), per-lane l accumulation.
__global__ void __launch_bounds__(256, 3)
attn(const unsigned short* __restrict__ qT, const unsigned short* __restrict__ kT,
     const unsigned short* __restrict__ vv,
     unsigned short* __restrict__ OP, float* __restrict__ lp, int S) {
    int combo = blockIdx.x;
    int b = combo / S, s = combo % S;
    int njt = 128 / S;
    int t = threadIdx.x, w = t >> 6, l = t & 63;
    int lr = l & 15, lg = l >> 4;
    int i0 = blockIdx.y * 64 + w * 16;

    __shared__ unsigned short Ks[32 * 256];     // 16KB, XOR-swizzled rows
    __shared__ unsigned short P_lds[4][512];    // per-wave 16x32 bf16
    unsigned short* pl = P_lds[w];

    const unsigned short* qb = qT + ((size_t)b * Nn + i0) * Cc;
    const char* kB = (const char*)(kT + (size_t)b * Nn * Cc);
    const unsigned short* vb = vv + (size_t)b * Cc * Nn;

    s16x8 qf[8];
#pragma unroll
    for (int kk = 0; kk < 8; kk++)
        qf[kk] = *(const s16x8*)(qb + lr * Cc + kk * 32 + lg * 8);

    f32x4 O[16];
#pragma unroll
    for (int ct = 0; ct < 16; ct++) O[ct] = {0, 0, 0, 0};
    float lsum[4] = {0, 0, 0, 0};
    const float L2E = 1.44269504088896340736f;
    const char* ksb = (const char*)Ks;
    int xorv = (lr & 7) << 4;
    int colb = lg * 16;

    for (int jt = 0; jt < njt; jt++) {
        int j0 = (s * njt + jt) * 32;
        __syncthreads();  // all waves done reading Ks from previous iter
        {
            const char* kslice = kB + (size_t)j0 * (Cc * 2);
#pragma unroll
            for (int i = 0; i < 4; i++) {
                unsigned chunk = w + i * 4;              // 16 x 1KB chunks
                unsigned L = chunk * 1024 + l * 16;      // byte offset in 16KB tile
                unsigned row = L >> 9;                   // 512B per K row
                GL16(kslice + (L ^ ((row & 7) << 4)), (char*)Ks + chunk * 1024);
            }
        }
        // V direct from L2 (independent; drained by the same vmcnt)
        s16x8 vf[16];
#pragma unroll
        for (int ct = 0; ct < 16; ct++)
            vf[ct] = *(const s16x8*)(vb + (size_t)(ct * 16 + lr) * Nn + j0 + lg * 8);
        asm volatile("s_waitcnt vmcnt(0)" ::: "memory");
        __syncthreads();

        // ---- QK^T from LDS (swizzled reads) ----
        f32x4 E0a = {0, 0, 0, 0}, E0b = {0, 0, 0, 0}, E1a = {0, 0, 0, 0}, E1b = {0, 0, 0, 0};
#pragma unroll
        for (int kk = 0; kk < 8; kk += 2) {
            int cb0 = (kk * 64 + colb) ^ xorv;
            int cb1 = ((kk + 1) * 64 + colb) ^ xorv;
            s16x8 k0a = *(const s16x8*)(ksb + lr * 512 + cb0);
            s16x8 k1a = *(const s16x8*)(ksb + (16 + lr) * 512 + cb0);
            s16x8 k0b = *(const s16x8*)(ksb + lr * 512 + cb1);
            s16x8 k1b = *(const s16x8*)(ksb + (16 + lr) * 512 + cb1);
            E0a = mfma16(qf[kk], k0a, E0a);
            E1a = mfma16(qf[kk], k1a, E1a);
            E0b = mfma16(qf[kk + 1], k0b, E0b);
            E1b = mfma16(qf[kk + 1], k1b, E1b);
        }
        f32x4 E0 = E0a + E0b, E1 = E1a + E1b;

        // ---- shift-free softmax: p = exp(E); per-lane partial row sums ----
        float p0[4], p1[4];
#pragma unroll
        for (int r = 0; r < 4; r++) {
            p0[r] = exp2f(E0[r] * L2E);
            p1[r] = exp2f(E1[r] * L2E);
            lsum[r] += p0[r] + p1[r];
        }
        // ---- P -> bf16 -> LDS roundtrip into A-frag layout (wave-synchronous) ----
#pragma unroll
        for (int r = 0; r < 4; r++) {
            pl[(lg * 4 + r) * 32 + lr] = f2bf(p0[r]);
            pl[(lg * 4 + r) * 32 + 16 + lr] = f2bf(p1[r]);
        }
        asm volatile("s_waitcnt lgkmcnt(0)" ::: "memory");
        s16x8 pf = *(const s16x8*)(pl + lr * 32 + lg * 8);
        // ---- PV ----
#pragma unroll
        for (int ct = 0; ct < 16; ct++)
            O[ct] = mfma16(pf, vf[ct], O[ct]);
    }

    // ---- reduce l across the 16 lanes of each row group, write partials ----
#pragma unroll
    for (int r = 0; r < 4; r++) {
#pragma unroll
        for (int msk = 1; msk <= 8; msk <<= 1)
            lsum[r] += __shfl_xor(lsum[r], msk);
    }
    if (lr == 0) {
#pragma unroll
        for (int r = 0; r < 4; r++)
            lp[((size_t)(s * Bb + b)) * Nn + i0 + lg * 4 + r] = lsum[r];
    }
    unsigned short* opb = OP + ((size_t)(s * Bb + b) * Cc) * Nn;
#pragma unroll
    for (int ct = 0; ct < 16; ct++) {
        s16x4 o4;
        o4[0] = (short)f2bf(O[ct][0]);
        o4[1] = (short)f2bf(O[ct][1]);
        o4[2] = (short)f2bf(O[ct][2]);
        o4[3] = (short)f2bf(O[ct][3]);
        *(s16x4*)(opb + (size_t)(ct * 16 + lr) * Nn + i0 + lg * 4) = o4;
    }
}

// ---------------- merge partials + epilogue ----------------
__global__ void __launch_bounds__(256)
merge(const unsigned short* __restrict__ OP, const float* __restrict__ lp,
      const float* __restrict__ x, const float* __restrict__ gamma,
      float* __restrict__ out, int S) {
    int b = blockIdx.z, c0 = blockIdx.y * 32, n0 = blockIdx.x * 64;
    __shared__ float linv[64];
    int t = threadIdx.x;
    if (t < 64) {
        float sum = 0.f;
        for (int si = 0; si < S; si++)
            sum += lp[((size_t)(si * Bb + b)) * Nn + n0 + t];
        linv[t] = 1.0f / sum;
    }
    __syncthreads();
    int tc = t >> 3, tn = (t & 7) * 8;
    int c = c0 + tc;
    float acc[8] = {0, 0, 0, 0, 0, 0, 0, 0};
    for (int si = 0; si < S; si++) {
        s16x8 o = *(const s16x8*)(OP + ((size_t)(si * Bb + b) * Cc + c) * Nn + n0 + tn);
#pragma unroll
        for (int j = 0; j < 8; j++) acc[j] += bf2f((unsigned short)o[j]);
    }
    float g = gamma[0];
    const float* xp = x + ((size_t)b * Cc + c) * Nn + n0 + tn;
    float* op = out + ((size_t)b * Cc + c) * Nn + n0 + tn;
    float4 r0, r1;
    r0.x = g * acc[0] * linv[tn + 0] + xp[0];
    r0.y = g * acc[1] * linv[tn + 1] + xp[1];
    r0.z = g * acc[2] * linv[tn + 2] + xp[2];
    r0.w = g * acc[3] * linv[tn + 3] + xp[3];
    r1.x = g * acc[4] * linv[tn + 4] + xp[4];
    r1.y = g * acc[5] * linv[tn + 5] + xp[5];
    r1.z = g * acc[6] * linv[tn + 6] + xp[6];
    r1.w = g * acc[7] * linv[tn + 7] + xp[7];
    *(float4*)op = r0;
    *(float4*)(op + 4) = r1;
}

extern "C" void kernel_launch(void* const* d_in, const int* in_sizes, int n_in,
                              void* d_out, int out_size, void* d_ws, size_t ws_size,
                              hipStream_t stream) {
    (void)in_sizes; (void)n_in; (void)out_size;
    const float* x     = (const float*)d_in[0];
    const float* Wq    = (const float*)d_in[1];
    const float* bq    = (const float*)d_in[2];
    const float* Wk    = (const float*)d_in[3];
    const float* bk    = (const float*)d_in[4];
    const float* Wv    = (const float*)d_in[5];
    const float* bv    = (const float*)d_in[6];
    const float* gamma = (const float*)d_in[7];
    float* out = (float*)d_out;

    const size_t XTN = (size_t)Bb * Nn * Cc;  // 4,194,304 elements
    unsigned short* xT  = (unsigned short*)d_ws;
    unsigned short* Wbf = xT + XTN;
    unsigned short* qT  = Wbf + 3 * Cc * Cc;
    unsigned short* kT  = qT + XTN;
    unsigned short* vv  = kT + XTN;
    unsigned short* OP  = vv + XTN;
    size_t fixed_bytes = (4 * XTN + (size_t)3 * Cc * Cc) * 2;
    int S = 8;
    while (S > 1 &&
           fixed_bytes + (size_t)S * (XTN * 2 + (size_t)Bb * Nn * 4) > ws_size)
        S >>= 1;
    float* lp = (float*)(OP + (size_t)S * XTN);

    hipLaunchKernelGGL(prep_w, dim3(96), dim3(256), 0, stream, Wq, Wk, Wv, Wbf);
    hipLaunchKernelGGL(transpose_x, dim3(Nn / 64, Cc / 64, Bb), dim3(256), 0, stream, x, xT);
    hipLaunchKernelGGL(proj, dim3(Nn / 64, 3, Bb), dim3(256), 0, stream,
                       xT, Wbf, bq, bk, bv, qT, kT, vv);
    hipLaunchKernelGGL(attn, dim3(Bb * S, Nn / 64), dim3(256), 0, stream,
                       qT, kT, vv, OP, lp, S);
    hipLaunchKernelGGL(merge, dim3(Nn / 64, Cc / 32, Bb), dim3(256), 0, stream,
                       OP, lp, x, gamma, out, S);
}